// Round 2
// baseline (261.724 us; speedup 1.0000x reference)
//
#include <hip/hip_runtime.h>
#include <hip/hip_bf16.h>

#define HS 128
#define NVT 32
#define NN 256

typedef __attribute__((ext_vector_type(8))) short bf16x8;
typedef __attribute__((ext_vector_type(4))) float f32x4;

// ws layout (bytes):
//   [0, 8388608)            cnt bf16 [512][256][32]
//   [8388608, 8421376)      TABB bf16 [512][32]  rows 0..383: GW[t][g] stored [g][t]; rows 384..511: G[t][h] stored [384+h][t]
//   [8421376, 8470528)      GIT float [32][384]  = W_ih[g][t] + b_ih[g] (+ b_hh[g] for g<256)
#define CNT_OFF  0
#define TABB_OFF 8388608
#define GIT_OFF  8421376

static __device__ __forceinline__ short f2bs(float f) {
    __hip_bfloat16 h = __float2bfloat16(f);
    short s; __builtin_memcpy(&s, &h, 2);
    return s;
}

// ---------------- Kernel A: tiny tables (all inputs fp32) -------------------
__global__ void __launch_bounds__(512) build_tables(
    const float* __restrict__ W_ih, const float* __restrict__ W_hh,
    const float* __restrict__ b_ih, const float* __restrict__ b_hh,
    const float* __restrict__ Wg,   const float* __restrict__ bg,
    const float* __restrict__ Wm,
    short* __restrict__ TABB, float* __restrict__ GIT)
{
    __shared__ float G_s[HS];
    const int t = blockIdx.x;          // vertex type
    const int j = threadIdx.x;
    if (j < HS) {
        float x = Wg[j * NVT + t] + bg[j];
        float sg = __builtin_amdgcn_rcpf(1.f + __expf(-x));
        G_s[j] = sg * Wm[j * NVT + t];
    }
    __syncthreads();
    if (j < 384) {
        float acc = 0.f;
        for (int h = 0; h < HS; ++h) acc += G_s[h] * W_hh[j * HS + h];
        TABB[j * NVT + t] = f2bs(acc);                       // GW[t][j] at [j][t]
        float git = W_ih[j * NVT + t] + b_ih[j];
        if (j < 256) git += b_hh[j];                          // fold b_hh for r,z only
        GIT[t * 384 + j] = git;
    } else {
        TABB[j * NVT + t] = f2bs(G_s[j - 384]);               // G[t][h] at [384+h][t]
    }
}

// ---------------- Kernel B: predecessor-type histograms ---------------------
__global__ void __launch_bounds__(256) count_preds(
    const int* __restrict__ node_types, const int* __restrict__ adj,
    short* __restrict__ cnt_out)
{
    __shared__ int cnt_s[NN * 33];     // stride 33: bank = (v + t) % 32 -> 2-way, free
    __shared__ int types_s[NN];
    const int b = blockIdx.x;
    const int tid = threadIdx.x;
    for (int i = tid; i < NN * 33; i += 256) cnt_s[i] = 0;
    types_s[tid] = node_types[b * NN + tid];
    __syncthreads();

    const int* adjb = adj + (size_t)b * NN * NN;
    const int v = tid;
    #pragma unroll 5
    for (int u = 0; u < 255; ++u) {    // row 255 is all-zero (strict upper-tri)
        int a = adjb[u * NN + v];      // coalesced 1KB per u
        int t = types_s[u];            // broadcast
        cnt_s[v * 33 + t] += a;        // a in {0,1}; unconditional avoids divergence
    }
    __syncthreads();

    // pack rows to bf16 (counts <= 255: exact) and store coalesced
    unsigned int* dst = (unsigned int*)cnt_out + (size_t)b * 4096;
    for (int i = tid; i < 4096; i += 256) {
        int vv = i >> 4, j2 = (i & 15) * 2;
        unsigned short lo = (unsigned short)f2bs((float)cnt_s[vv * 33 + j2]);
        unsigned short hi = (unsigned short)f2bs((float)cnt_s[vv * 33 + j2 + 1]);
        dst[i] = (unsigned int)lo | ((unsigned int)hi << 16);
    }
}

// ---------------- Kernel C: MFMA GEMMs + fused GRU + readout ----------------
__global__ void __launch_bounds__(256) grue_main(
    const int* __restrict__ node_types,
    const short* __restrict__ cnt_ws, const short* __restrict__ TABB,
    const float* __restrict__ GIT,    const float* __restrict__ b_hh,
    const float* __restrict__ W1, const float* __restrict__ b1,
    const float* __restrict__ W2, const float* __restrict__ b2,
    float* __restrict__ out)
{
    __shared__ short cntA[NN * 40];    // bf16 counts, stride 40 (pad for b128 reads)
    __shared__ float ghT[16 * 388];    // gh tile [16 v][384 g], stride 388
    __shared__ float HpT[16 * 132];    // Hpre tile [16 v][128 h], stride 132
    __shared__ int   types_s[NN];
    __shared__ float hg_s[NN];

    const int b = blockIdx.x;
    const int tid = threadIdx.x;
    const int wave = tid >> 6, lane = tid & 63;
    const int quad = lane >> 4, col = lane & 15;

    types_s[tid] = node_types[b * NN + tid];
    {   // stage counts: row tid (64B) as 4x uint4
        const uint4* src = (const uint4*)cnt_ws + (size_t)b * 1024 + tid * 4;
        uint4* dstl = (uint4*)cntA;
        #pragma unroll
        for (int c = 0; c < 4; ++c) dstl[tid * 5 + c] = src[c];
    }
    // register-resident B fragments: wave w owns g in [w*96, w*96+96) (6 tiles)
    // and h in [w*32, w*32+32) (2 tiles). B[k=t][n]: lane reads 8 consecutive t of row jb+col.
    bf16x8 bfrag[8];
    #pragma unroll
    for (int i = 0; i < 8; ++i) {
        int jb = (i < 6) ? (wave * 96 + i * 16) : (384 + wave * 32 + (i - 6) * 16);
        bfrag[i] = *(const bf16x8*)(TABB + (jb + col) * 32 + quad * 8);
    }
    const int eh = tid & 127;                 // epilogue h
    const int esub = (tid >> 7) * 8;          // epilogue v-subrange
    const float bhn = b_hh[256 + eh];         // b_hh n-part stays inside r*(.)
    float hg_acc = 0.f;
    __syncthreads();

    for (int m = 0; m < 16; ++m) {
        // A frag: A[m=lane&15][k=quad*8+j], one ds_read_b128, K=32 in one MFMA
        bf16x8 afrag = *(const bf16x8*)(cntA + (m * 16 + col) * 40 + quad * 8);
        f32x4 acc[8];
        #pragma unroll
        for (int i = 0; i < 8; ++i)
            acc[i] = __builtin_amdgcn_mfma_f32_16x16x32_bf16(
                afrag, bfrag[i], (f32x4){0.f, 0.f, 0.f, 0.f}, 0, 0, 0);
        __syncthreads();   // prev epilogue done reading ghT/HpT
        // C/D: col = lane&15 (n), row = quad*4 + r (m)
        #pragma unroll
        for (int i = 0; i < 6; ++i) {
            int g = wave * 96 + i * 16 + col;
            #pragma unroll
            for (int r = 0; r < 4; ++r) ghT[(quad * 4 + r) * 388 + g] = acc[i][r];
        }
        #pragma unroll
        for (int i = 6; i < 8; ++i) {
            int h2 = wave * 32 + (i - 6) * 16 + col;
            #pragma unroll
            for (int r = 0; r < 4; ++r) HpT[(quad * 4 + r) * 132 + h2] = acc[i][r];
        }
        __syncthreads();
        // fused GRU epilogue: 16 v x 128 h, 8 v per thread
        #pragma unroll
        for (int vl8 = 0; vl8 < 8; ++vl8) {
            int vl = esub + vl8;
            int v = m * 16 + vl;
            int tv = types_s[v];
            const float* git = GIT + tv * 384 + eh;   // coalesced over eh
            float gir = git[0], giz = git[128], gin = git[256];
            float ghr = ghT[vl * 388 + eh];
            float ghz = ghT[vl * 388 + 128 + eh];
            float ghn = ghT[vl * 388 + 256 + eh] + bhn;
            float hp  = HpT[vl * 132 + eh];
            float r = __builtin_amdgcn_rcpf(1.f + __expf(-(gir + ghr)));
            float z = __builtin_amdgcn_rcpf(1.f + __expf(-(giz + ghz)));
            float n = 1.f - 2.f * __builtin_amdgcn_rcpf(1.f + __expf(2.f * (gin + r * ghn)));
            float hv = (1.f - z) * n + z * hp;
            float msk = (v >= 1 && v < 255) ? 1.f : 0.f;   // Hg sums v in [1,254]
            hg_acc += msk * hv;
        }
    }
    hg_s[tid] = hg_acc;
    __syncthreads();
    if (tid < 128) hg_s[tid] = hg_s[tid] + hg_s[tid + 128];
    __syncthreads();
    // fused readout: mu (tid<64) / logvar (64<=tid<128)
    if (tid < 128) {
        int which = tid >> 6, zz = tid & 63;
        const float* W = which ? W2 : W1;
        float acc2 = (which ? b2[zz] : b1[zz]);
        for (int h = 0; h < HS; ++h) acc2 += hg_s[h] * W[zz * HS + h];
        out[which * 32768 + b * 64 + zz] = acc2;
    }
}

extern "C" void kernel_launch(void* const* d_in, const int* in_sizes, int n_in,
                              void* d_out, int out_size, void* d_ws, size_t ws_size,
                              hipStream_t stream)
{
    const int* node_types = (const int*)d_in[0];
    const int* adj        = (const int*)d_in[1];
    const float* W_ih = (const float*)d_in[2];
    const float* W_hh = (const float*)d_in[3];
    const float* b_ih = (const float*)d_in[4];
    const float* b_hh = (const float*)d_in[5];
    const float* Wg   = (const float*)d_in[6];
    const float* bg   = (const float*)d_in[7];
    const float* Wm   = (const float*)d_in[8];
    const float* W1   = (const float*)d_in[9];
    const float* b1   = (const float*)d_in[10];
    const float* W2   = (const float*)d_in[11];
    const float* b2   = (const float*)d_in[12];

    char* ws = (char*)d_ws;
    short* cnt_ws = (short*)(ws + CNT_OFF);
    short* TABB   = (short*)(ws + TABB_OFF);
    float* GIT    = (float*)(ws + GIT_OFF);
    float* out    = (float*)d_out;

    build_tables<<<dim3(32), dim3(512), 0, stream>>>(W_ih, W_hh, b_ih, b_hh, Wg, bg, Wm, TABB, GIT);
    count_preds<<<dim3(512), dim3(256), 0, stream>>>(node_types, adj, cnt_ws);
    grue_main<<<dim3(512), dim3(256), 0, stream>>>(node_types, cnt_ws, TABB, GIT, b_hh, W1, b1, W2, b2, out);
}

// Round 3
// 247.772 us; speedup vs baseline: 1.0563x; 1.0563x over previous
//
#include <hip/hip_runtime.h>
#include <hip/hip_bf16.h>

#define HS 128
#define NVT 32
#define NN 256

typedef __attribute__((ext_vector_type(8))) short bf16x8;
typedef __attribute__((ext_vector_type(4))) float f32x4;

// ws layout (bytes):
//   [0, 32768)       TABB bf16 [512][32]: rows 0..383 = GW[t][g] at [g][t]; rows 384..511 = G[t][h] at [384+h][t]
//   [32768, 57344)   GIT  bf16 [32][384]: W_ih[g][t]+b_ih[g] (+b_hh[g] for g<256)
#define TABB_OFF 0
#define GIT_OFF  32768

static __device__ __forceinline__ short f2bs(float f) {
    __hip_bfloat16 h = __float2bfloat16(f);
    short s; __builtin_memcpy(&s, &h, 2);
    return s;
}
static __device__ __forceinline__ float bs2f(short s) {
    __hip_bfloat16 h; __builtin_memcpy(&h, &s, 2);
    return __bfloat162float(h);
}
static __device__ __forceinline__ float sigm(float x) {
    return __builtin_amdgcn_rcpf(1.f + __expf(-x));
}

// ---------------- Kernel A: tiny tables (fp32 inputs) -----------------------
__global__ void __launch_bounds__(512) build_tables(
    const float* __restrict__ W_ih, const float* __restrict__ W_hh,
    const float* __restrict__ b_ih, const float* __restrict__ b_hh,
    const float* __restrict__ Wg,   const float* __restrict__ bg,
    const float* __restrict__ Wm,
    short* __restrict__ TABB, short* __restrict__ GIT)
{
    __shared__ float G_s[HS];
    const int t = blockIdx.x;          // vertex type
    const int j = threadIdx.x;
    if (j < HS) {
        float x = Wg[j * NVT + t] + bg[j];
        G_s[j] = sigm(x) * Wm[j * NVT + t];
    }
    __syncthreads();
    if (j < 384) {
        float acc = 0.f;
        for (int h = 0; h < HS; ++h) acc += G_s[h] * W_hh[j * HS + h];
        TABB[j * NVT + t] = f2bs(acc);                        // GW[t][j] at [j][t]
        float git = W_ih[j * NVT + t] + b_ih[j];
        if (j < 256) git += b_hh[j];                          // fold b_hh for r,z only
        GIT[t * 384 + j] = f2bs(git);
    } else {
        TABB[j * NVT + t] = f2bs(G_s[j - 384]);               // G[t][h] at [384+h][t]
    }
}

// ---------------- Kernel B: fused histogram + MFMA + GRU + readout ----------
__global__ void __launch_bounds__(256) dvae_fused(
    const int* __restrict__ node_types, const int* __restrict__ adj,
    const short* __restrict__ TABB, const short* __restrict__ GIT,
    const float* __restrict__ b_hh,
    const float* __restrict__ W1, const float* __restrict__ b1,
    const float* __restrict__ W2, const float* __restrict__ b2,
    float* __restrict__ out)
{
    __shared__ short cntA[NN * 40];     // bf16 counts, row stride 40 (16B-aligned b128 reads)
    __shared__ short GITs[NVT * 388];   // bf16 GIT rows, stride 388
    __shared__ int   types_s[NN];
    __shared__ float hgp[4 * HS];       // per-quad Hg partials
    __shared__ float hg_s[HS];

    const int b = blockIdx.x, tid = threadIdx.x;
    const int wave = tid >> 6, lane = tid & 63;
    const int quad = lane >> 4, col = lane & 15;

    types_s[tid] = node_types[b * NN + tid];

    // stage GIT (32x384 bf16 = 6144 uints) -> LDS rows stride 388 shorts (194 uints)
    {
        const unsigned* src = (const unsigned*)GIT;
        unsigned* dst = (unsigned*)GITs;
        #pragma unroll
        for (int c = 0; c < 24; ++c) {
            int i = c * 256 + tid;          // i < 6144
            int t = i / 192, j = i - t * 192;
            dst[t * 194 + j] = src[i];
        }
    }

    // ---- phase 1: predecessor-type histogram, register-packed ----
    // thread v keeps 32 byte-counters in c0..c7 (4 per reg); t is wave-uniform.
    const int* adjb = adj + (size_t)b * NN * NN;
    const int v = tid;
    unsigned c0 = 0, c1 = 0, c2 = 0, c3 = 0, c4 = 0, c5 = 0, c6 = 0, c7 = 0;
    for (int u0 = 0; u0 < NN; u0 += 32) {   // row 255 all-zero: harmless
        int av[32];
        #pragma unroll
        for (int j = 0; j < 32; ++j) av[j] = adjb[(u0 + j) * NN + v];
        #pragma unroll
        for (int j = 0; j < 32; ++j) {
            unsigned t = (unsigned)__builtin_amdgcn_readfirstlane(types_s[u0 + j]);
            unsigned inc = ((unsigned)av[j]) << ((t & 3u) * 8u);
            switch (t >> 2) {               // wave-uniform -> scalar branches
                case 0: c0 += inc; break;
                case 1: c1 += inc; break;
                case 2: c2 += inc; break;
                case 3: c3 += inc; break;
                case 4: c4 += inc; break;
                case 5: c5 += inc; break;
                case 6: c6 += inc; break;
                default: c7 += inc; break;
            }
        }
    }
    {   // unpack to bf16 pairs (counts <= 255: exact in bf16)
        unsigned cc[8] = {c0, c1, c2, c3, c4, c5, c6, c7};
        unsigned* dst = (unsigned*)cntA;    // row stride 20 uints
        #pragma unroll
        for (int k = 0; k < 8; ++k) {
            float f0 = (float)(cc[k] & 0xFF),         f1 = (float)((cc[k] >> 8) & 0xFF);
            float f2 = (float)((cc[k] >> 16) & 0xFF), f3 = (float)((cc[k] >> 24) & 0xFF);
            unsigned p0 = (unsigned)(unsigned short)f2bs(f0) | ((unsigned)(unsigned short)f2bs(f1) << 16);
            unsigned p1 = (unsigned)(unsigned short)f2bs(f2) | ((unsigned)(unsigned short)f2bs(f3) << 16);
            dst[v * 20 + 2 * k]     = p0;
            dst[v * 20 + 2 * k + 1] = p1;
        }
    }

    // ---- B fragments: wave w owns h in [w*32, w*32+32): tiles r,z,n gates + Hpre ----
    bf16x8 bfrag[8];
    #pragma unroll
    for (int i = 0; i < 8; ++i) {
        int gate = i >> 1, sub = (i & 1) * 16;
        int jb = (gate < 3 ? gate * 128 : 384) + wave * 32 + sub;
        bfrag[i] = *(const bf16x8*)(TABB + (jb + col) * 32 + quad * 8);
    }
    const int h0 = wave * 32 + col;         // +16 for hb=1
    const float bhn0 = b_hh[256 + h0], bhn1 = b_hh[256 + h0 + 16];
    float hg0 = 0.f, hg1 = 0.f;
    __syncthreads();

    // ---- phase 2: 16 m-tiles, barrier-free, in-register GRU epilogue ----
    for (int m = 0; m < 16; ++m) {
        bf16x8 afrag = *(const bf16x8*)(cntA + (m * 16 + col) * 40 + quad * 8);
        f32x4 acc[8];
        #pragma unroll
        for (int i = 0; i < 8; ++i)
            acc[i] = __builtin_amdgcn_mfma_f32_16x16x32_bf16(
                afrag, bfrag[i], (f32x4){0.f, 0.f, 0.f, 0.f}, 0, 0, 0);
        // C/D: col = n (h-offset), row = quad*4 + r (v-offset)
        #pragma unroll
        for (int r = 0; r < 4; ++r) {
            int vv = m * 16 + quad * 4 + r;
            int tv = types_s[vv];
            float msk = (vv >= 1 && vv < NN - 1) ? 1.f : 0.f;
            const short* g = GITs + tv * 388;
            {   // hb = 0
                float gir = bs2f(g[h0]), giz = bs2f(g[128 + h0]), gin = bs2f(g[256 + h0]);
                float rr = sigm(gir + acc[0][r]);
                float zz = sigm(giz + acc[2][r]);
                float x2 = gin + rr * (acc[4][r] + bhn0);
                float nt = 1.f - 2.f * __builtin_amdgcn_rcpf(1.f + __expf(2.f * x2));
                hg0 += msk * ((1.f - zz) * nt + zz * acc[6][r]);
            }
            {   // hb = 1
                int h1 = h0 + 16;
                float gir = bs2f(g[h1]), giz = bs2f(g[128 + h1]), gin = bs2f(g[256 + h1]);
                float rr = sigm(gir + acc[1][r]);
                float zz = sigm(giz + acc[3][r]);
                float x2 = gin + rr * (acc[5][r] + bhn1);
                float nt = 1.f - 2.f * __builtin_amdgcn_rcpf(1.f + __expf(2.f * x2));
                hg1 += msk * ((1.f - zz) * nt + zz * acc[7][r]);
            }
        }
    }

    // ---- Hg reduce (4 quads) + fused readout ----
    hgp[quad * HS + h0]      = hg0;
    hgp[quad * HS + h0 + 16] = hg1;
    __syncthreads();
    if (tid < HS)
        hg_s[tid] = (hgp[tid] + hgp[HS + tid]) + (hgp[2 * HS + tid] + hgp[3 * HS + tid]);
    __syncthreads();
    if (tid < 128) {
        int which = tid >> 6, zz = tid & 63;
        const float* W = which ? W2 : W1;
        float acc2 = which ? b2[zz] : b1[zz];
        #pragma unroll 4
        for (int h = 0; h < HS; ++h) acc2 += hg_s[h] * W[zz * HS + h];
        out[which * 32768 + b * 64 + zz] = acc2;
    }
}

extern "C" void kernel_launch(void* const* d_in, const int* in_sizes, int n_in,
                              void* d_out, int out_size, void* d_ws, size_t ws_size,
                              hipStream_t stream)
{
    const int* node_types = (const int*)d_in[0];
    const int* adj        = (const int*)d_in[1];
    const float* W_ih = (const float*)d_in[2];
    const float* W_hh = (const float*)d_in[3];
    const float* b_ih = (const float*)d_in[4];
    const float* b_hh = (const float*)d_in[5];
    const float* Wg   = (const float*)d_in[6];
    const float* bg   = (const float*)d_in[7];
    const float* Wm   = (const float*)d_in[8];
    const float* W1   = (const float*)d_in[9];
    const float* b1   = (const float*)d_in[10];
    const float* W2   = (const float*)d_in[11];
    const float* b2   = (const float*)d_in[12];

    char* ws = (char*)d_ws;
    short* TABB = (short*)(ws + TABB_OFF);
    short* GIT  = (short*)(ws + GIT_OFF);
    float* out  = (float*)d_out;

    build_tables<<<dim3(32), dim3(512), 0, stream>>>(W_ih, W_hh, b_ih, b_hh, Wg, bg, Wm, TABB, GIT);
    dvae_fused<<<dim3(512), dim3(256), 0, stream>>>(node_types, adj, TABB, GIT, b_hh, W1, b1, W2, b2, out);
}

// Round 4
// 241.789 us; speedup vs baseline: 1.0825x; 1.0247x over previous
//
#include <hip/hip_runtime.h>
#include <hip/hip_bf16.h>

#define HS 128
#define NVT 32
#define NN 256

typedef __attribute__((ext_vector_type(8))) short bf16x8;
typedef __attribute__((ext_vector_type(4))) float f32x4;

// ws layout (bytes):
//   [0, 32768)       TABB bf16 [512][32]: rows 0..383 = GW[t][g] at [g][t]; rows 384..511 = G[t][h] at [384+h][t]
//   [32768, 57344)   GIT  bf16 [32][384]: W_ih[g][t]+b_ih[g] (+b_hh[g] for g<256)
#define TABB_OFF 0
#define GIT_OFF  32768

static __device__ __forceinline__ short f2bs(float f) {
    __hip_bfloat16 h = __float2bfloat16(f);
    short s; __builtin_memcpy(&s, &h, 2);
    return s;
}
static __device__ __forceinline__ float bs2f(short s) {
    __hip_bfloat16 h; __builtin_memcpy(&h, &s, 2);
    return __bfloat162float(h);
}
static __device__ __forceinline__ float sigm(float x) {
    return __builtin_amdgcn_rcpf(1.f + __expf(-x));
}

// ---------------- Kernel A: tiny tables (fp32 inputs) -----------------------
__global__ void __launch_bounds__(512) build_tables(
    const float* __restrict__ W_ih, const float* __restrict__ W_hh,
    const float* __restrict__ b_ih, const float* __restrict__ b_hh,
    const float* __restrict__ Wg,   const float* __restrict__ bg,
    const float* __restrict__ Wm,
    short* __restrict__ TABB, short* __restrict__ GIT)
{
    __shared__ float G_s[HS];
    const int t = blockIdx.x;          // vertex type
    const int j = threadIdx.x;
    if (j < HS) {
        float x = Wg[j * NVT + t] + bg[j];
        G_s[j] = sigm(x) * Wm[j * NVT + t];
    }
    __syncthreads();
    if (j < 384) {
        float acc = 0.f;
        for (int h = 0; h < HS; ++h) acc += G_s[h] * W_hh[j * HS + h];
        TABB[j * NVT + t] = f2bs(acc);                        // GW[t][j] at [j][t]
        float git = W_ih[j * NVT + t] + b_ih[j];
        if (j < 256) git += b_hh[j];                          // fold b_hh for r,z only
        GIT[t * 384 + j] = f2bs(git);
    } else {
        TABB[j * NVT + t] = f2bs(G_s[j - 384]);               // G[t][h] at [384+h][t]
    }
}

// ---------------- Kernel B: fused histogram + MFMA + GRU + readout ----------
__global__ void __launch_bounds__(512) dvae_fused(
    const int* __restrict__ node_types, const int* __restrict__ adj,
    const short* __restrict__ TABB, const short* __restrict__ GIT,
    const float* __restrict__ b_hh,
    const float* __restrict__ W1, const float* __restrict__ b1,
    const float* __restrict__ W2, const float* __restrict__ b2,
    float* __restrict__ out)
{
    __shared__ unsigned cntA[NN * 20];   // bf16 count pairs, row = 16 u32 + 4 pad (16B-aligned b128)
    __shared__ short GITs[NVT * 388];    // bf16 GIT rows, stride 388 shorts
    __shared__ unsigned tmask[NVT * 8];  // per-type row bitmasks [t][w8]
    __shared__ int types_s[NN];
    __shared__ float hg_s[HS];

    const int b = blockIdx.x, tid = threadIdx.x;     // 512 threads = 8 waves
    const int wave = tid >> 6, lane = tid & 63;
    const int quad = lane >> 4, col = lane & 15;

    if (tid < NN) types_s[tid] = node_types[b * NN + tid];

    // stage GIT (6144 uints) -> LDS rows stride 194 uints
    {
        const unsigned* src = (const unsigned*)GIT;
        unsigned* dst = (unsigned*)GITs;
        #pragma unroll
        for (int c = 0; c < 12; ++c) {
            int i = c * 512 + tid;
            int t = i / 192, j = i - t * 192;
            dst[t * 194 + j] = src[i];
        }
    }

    // B fragments + bias (global loads, independent of LDS) — all 8 waves.
    // Wave w owns h-slice [w*16, w*16+16): gate tiles r,z,n + Hpre.
    bf16x8 bfrag[4];
    #pragma unroll
    for (int g = 0; g < 4; ++g) {
        int jb = (g < 3 ? g * 128 : 384) + wave * 16;
        bfrag[g] = *(const bf16x8*)(TABB + (jb + col) * 32 + quad * 8);
    }
    const int h0 = wave * 16 + col;
    const float bhn = b_hh[256 + h0];    // b_hh n-part stays inside r*(.)

    // ---- phase 1a: column adjacency bitmask (waves 0-3; thread = column v) ----
    unsigned cb[8];
    if (tid < NN) {
        const int* colp = adj + (size_t)b * NN * NN + tid;
        #pragma unroll
        for (int w8 = 0; w8 < 8; ++w8) {
            int avv[32];
            #pragma unroll
            for (int j = 0; j < 32; ++j) avv[j] = colp[(w8 * 32 + j) * NN];
            unsigned wd = 0;
            #pragma unroll
            for (int j = 0; j < 32; ++j) wd |= ((unsigned)avv[j]) << j;
            cb[w8] = wd;
        }
    }
    __syncthreads();                     // types_s, GITs ready

    // ---- phase 1b: per-type row bitmasks ----
    if (tid < NN) {
        int t = tid >> 3, w8 = tid & 7;
        unsigned mw = 0;
        #pragma unroll
        for (int k = 0; k < 32; ++k)
            mw |= ((unsigned)(types_s[w8 * 32 + k] == t)) << k;
        tmask[tid] = mw;
    }
    __syncthreads();

    // ---- phase 1c: popcount histogram -> exact bf16 pairs ----
    if (tid < NN) {
        #pragma unroll
        for (int tp = 0; tp < 16; ++tp) {
            const uint4* m0p = (const uint4*)&tmask[(2 * tp) * 8];      // wave-uniform -> broadcast
            const uint4* m1p = (const uint4*)&tmask[(2 * tp + 1) * 8];
            uint4 ma = m0p[0], mb = m0p[1], mc = m1p[0], md = m1p[1];
            unsigned c0 = __popc(cb[0] & ma.x) + __popc(cb[1] & ma.y)
                        + __popc(cb[2] & ma.z) + __popc(cb[3] & ma.w)
                        + __popc(cb[4] & mb.x) + __popc(cb[5] & mb.y)
                        + __popc(cb[6] & mb.z) + __popc(cb[7] & mb.w);
            unsigned c1 = __popc(cb[0] & mc.x) + __popc(cb[1] & mc.y)
                        + __popc(cb[2] & mc.z) + __popc(cb[3] & mc.w)
                        + __popc(cb[4] & md.x) + __popc(cb[5] & md.y)
                        + __popc(cb[6] & md.z) + __popc(cb[7] & md.w);
            // counts <= 255: bf16 exact = top 16 bits of fp32
            unsigned p = (__float_as_uint((float)c0) >> 16)
                       | (__float_as_uint((float)c1) & 0xFFFF0000u);
            cntA[tid * 20 + tp] = p;
        }
    }
    __syncthreads();

    // ---- phase 2: 16 m-tiles, in-register GRU epilogue, all 8 waves ----
    float hg = 0.f;
    for (int m = 0; m < 16; ++m) {
        bf16x8 afrag = *(const bf16x8*)(cntA + (m * 16 + col) * 20 + quad * 4);
        f32x4 acc[4];
        #pragma unroll
        for (int g = 0; g < 4; ++g)
            acc[g] = __builtin_amdgcn_mfma_f32_16x16x32_bf16(
                afrag, bfrag[g], (f32x4){0.f, 0.f, 0.f, 0.f}, 0, 0, 0);
        // C/D: col = n (h-offset), row = quad*4 + r (v within tile)
        #pragma unroll
        for (int r = 0; r < 4; ++r) {
            int vv = m * 16 + quad * 4 + r;
            int tv = types_s[vv];
            const short* g = GITs + tv * 388;
            float gir = bs2f(g[h0]);
            float giz = bs2f(g[128 + h0]);
            float gin = bs2f(g[256 + h0]);
            float rr = sigm(gir + acc[0][r]);
            float zz = sigm(giz + acc[1][r]);
            float x2 = gin + rr * (acc[2][r] + bhn);
            float nt = 1.f - 2.f * __builtin_amdgcn_rcpf(1.f + __expf(2.f * x2));
            float msk = (vv >= 1 && vv < NN - 1) ? 1.f : 0.f;   // Hg: v in [1,254]
            hg += msk * ((1.f - zz) * nt + zz * acc[3][r]);
        }
    }
    // reduce across the 4 quads (same h0, different v-rows)
    hg += __shfl_xor(hg, 16);
    hg += __shfl_xor(hg, 32);
    if (lane < 16) hg_s[h0] = hg;        // each h owned by exactly one wave
    __syncthreads();

    // ---- fused readout: mu (tid<64) / logvar (64<=tid<128) ----
    if (tid < 128) {
        int which = tid >> 6, zz = tid & 63;
        const float* W = which ? W2 : W1;
        float acc2 = which ? b2[zz] : b1[zz];
        const float4* Wv = (const float4*)(W + zz * HS);
        #pragma unroll
        for (int i = 0; i < 32; ++i) {
            float4 ww = Wv[i];
            acc2 += hg_s[4 * i] * ww.x + hg_s[4 * i + 1] * ww.y
                  + hg_s[4 * i + 2] * ww.z + hg_s[4 * i + 3] * ww.w;
        }
        out[which * 32768 + b * 64 + zz] = acc2;
    }
}

extern "C" void kernel_launch(void* const* d_in, const int* in_sizes, int n_in,
                              void* d_out, int out_size, void* d_ws, size_t ws_size,
                              hipStream_t stream)
{
    const int* node_types = (const int*)d_in[0];
    const int* adj        = (const int*)d_in[1];
    const float* W_ih = (const float*)d_in[2];
    const float* W_hh = (const float*)d_in[3];
    const float* b_ih = (const float*)d_in[4];
    const float* b_hh = (const float*)d_in[5];
    const float* Wg   = (const float*)d_in[6];
    const float* bg   = (const float*)d_in[7];
    const float* Wm   = (const float*)d_in[8];
    const float* W1   = (const float*)d_in[9];
    const float* b1   = (const float*)d_in[10];
    const float* W2   = (const float*)d_in[11];
    const float* b2   = (const float*)d_in[12];

    char* ws = (char*)d_ws;
    short* TABB = (short*)(ws + TABB_OFF);
    short* GIT  = (short*)(ws + GIT_OFF);
    float* out  = (float*)d_out;

    build_tables<<<dim3(32), dim3(512), 0, stream>>>(W_ih, W_hh, b_ih, b_hh, Wg, bg, Wm, TABB, GIT);
    dvae_fused<<<dim3(512), dim3(512), 0, stream>>>(node_types, adj, TABB, GIT, b_hh, W1, b1, W2, b2, out);
}